// Round 22
// baseline (97.617 us; speedup 1.0000x reference)
//
#include <hip/hip_runtime.h>

// LAPACK slartg vintage: 1 = LAPACK >= 3.10
#define SLARTG_NEW 1

namespace {

constexpr int KNN_K = 5;
constexpr int GRID = 16;                 // cells per axis; h = 1/16
constexpr int CELLS = GRID * GRID * GRID;
constexpr int LPG = 8;                   // lanes per point (KNN kernel)

// Solver launch geometry: pack 8 waves/block onto few CUs -> 2 waves/SIMD
// co-residency so independent solver chains fill each other's stalls.
constexpr int SOLVER_TPB = 512;

// Brute-force fallback config
constexpr int PPB = 16;
constexpr int STR = 16;
constexpr int TPB = PPB * STR;
constexpr int TILE = 2048;

// fp32 LAPACK machine constants (exact IEEE-single values)
#define EPSF    5.9604644775390625e-8f
#define EPS2F   3.552713678800501e-15f
#define SAFMINF 1.1754943508222875e-38f
#define SAFMAXF 8.507059173023462e+37f
#define RTMINF  1.0842021724855044e-19f
#define RTMAXF  9.223372036854776e+18f

// ---- fp32 helpers: ALL-PLAIN rounding (no-FMA reference stack, verified R7) ----
__device__ __forceinline__ float sqnorm3(float x, float y, float z) {
#pragma clang fp contract(off)
  float a = x * x;
  float b = y * y;
  float c = z * z;
  return (a + b) + c;
}

__device__ __forceinline__ float dist2(float xi, float yi, float zi, float sqi,
                                       float xj, float yj, float zj, float sqj) {
#pragma clang fp contract(off)
  float dot = (xi * xj + yi * yj) + zi * zj; // PLAIN, no FMA — verified R7
  float a = sqi + sqj;
  return a - 2.0f * dot;
}

__device__ __forceinline__ int cell1d(float v) {
  int c = (int)(v * (float)GRID);
  if (c < 0) c = 0;
  if (c > GRID - 1) c = GRID - 1;
  return c;
}

// ---- fp32 LAPACK ports (reference netlib, plain rounding) — verified R7 ----
__device__ __forceinline__ float slapy2f(float x, float y) {
#pragma clang fp contract(off)
  float xa = fabsf(x), ya = fabsf(y);
  float w = fmaxf(xa, ya);
  float z = fminf(xa, ya);
  if (z == 0.f) return w;
  float q = z / w;
  float q2 = q * q;
  float s = 1.0f + q2;
  return w * sqrtf(s);
}

__device__ __forceinline__ void slartgf(float f, float g, float* cs, float* sn, float* r) {
#pragma clang fp contract(off)
#if SLARTG_NEW
  float f1 = fabsf(f), g1 = fabsf(g);
  if (g == 0.f) { *cs = 1.f; *sn = 0.f; *r = f; }
  else if (f == 0.f) { *cs = 0.f; *sn = copysignf(1.f, g); *r = g1; }
  else if (f1 > RTMINF && f1 < RTMAXF && g1 > RTMINF && g1 < RTMAXF) {
    float ff = f * f;
    float gg = g * g;
    float d = sqrtf(ff + gg);
    *cs = f1 / d;
    float rr = copysignf(d, f);
    *sn = g / rr;
    *r = rr;
  } else {
    float u = fminf(SAFMAXF, fmaxf(fmaxf(SAFMINF, f1), g1));
    float fs = f / u, gs = g / u;
    float ff = fs * fs;
    float gg = gs * gs;
    float d = sqrtf(ff + gg);
    *cs = fabsf(fs) / d;
    float rr = copysignf(d, f);
    *sn = gs / rr;
    *r = rr * u;
  }
#else
  if (g == 0.f) { *cs = 1.f; *sn = 0.f; *r = f; }
  else if (f == 0.f) { *cs = 0.f; *sn = 1.f; *r = g; }
  else {
    float f2 = f * f;
    float g2 = g * g;
    float rr = sqrtf(f2 + g2);
    float c = f / rr, s = g / rr;
    if (fabsf(f) > fabsf(g) && c < 0.f) { c = -c; s = -s; rr = -rr; }
    *cs = c; *sn = s; *r = rr;
  }
#endif
}

__device__ __forceinline__ void slaev2f(float a, float b, float c,
                                        float* rt1, float* rt2, float* cs1, float* sn1) {
#pragma clang fp contract(off)
  float sm = a + c;
  float df = a - c;
  float adf = fabsf(df);
  float tb = b + b;
  float ab = fabsf(tb);
  float acmx, acmn;
  if (fabsf(a) > fabsf(c)) { acmx = a; acmn = c; } else { acmx = c; acmn = a; }
  float rt;
  if (adf > ab) { float q = ab / adf; rt = adf * sqrtf(1.0f + q * q); }
  else if (adf < ab) { float q = adf / ab; rt = ab * sqrtf(1.0f + q * q); }
  else rt = ab * sqrtf(2.0f);
  int sgn1;
  if (sm < 0.f) { *rt1 = 0.5f * (sm - rt); sgn1 = -1; *rt2 = (acmx / *rt1) * acmn - (b / *rt1) * b; }
  else if (sm > 0.f) { *rt1 = 0.5f * (sm + rt); sgn1 = 1; *rt2 = (acmx / *rt1) * acmn - (b / *rt1) * b; }
  else { *rt1 = 0.5f * rt; *rt2 = -0.5f * rt; sgn1 = 1; }
  float cs; int sgn2;
  if (df >= 0.f) { cs = df + rt; sgn2 = 1; } else { cs = df - rt; sgn2 = -1; }
  float acs = fabsf(cs);
  float c1, s1;
  if (acs > ab) {
    float ct = -tb / cs;
    s1 = 1.0f / sqrtf(1.0f + ct * ct);
    c1 = ct * s1;
  } else {
    if (ab == 0.f) { c1 = 1.f; s1 = 0.f; }
    else {
      float tn = -cs / tb;
      c1 = 1.0f / sqrtf(1.0f + tn * tn);
      s1 = tn * c1;
    }
  }
  if (sgn1 == sgn2) { float tn = c1; c1 = -s1; s1 = tn; }
  *cs1 = c1; *sn1 = s1;
}

__device__ __forceinline__ void slascl_g(float cfrom, float cto, int n, float* a) {
#pragma clang fp contract(off)
  float cfromc = cfrom, ctoc = cto;
  bool done = false;
  int guard = 0;
  while (!done && guard++ < 50) {
    float mul;
    float cfrom1 = cfromc * SAFMINF;
    if (cfrom1 == cfromc) {
      mul = ctoc / cfromc; done = true;
    } else {
      float cto1 = ctoc / SAFMAXF;
      if (cto1 == ctoc) { mul = ctoc; done = true; cfromc = 1.f; }
      else if (fabsf(cfrom1) > fabsf(ctoc) && ctoc != 0.f) { mul = SAFMINF; done = false; cfromc = cfrom1; }
      else if (fabsf(cto1) > fabsf(cfromc)) { mul = SAFMAXF; done = false; ctoc = cto1; }
      else { mul = ctoc / cfromc; done = true; }
    }
    for (int i = 0; i < n; ++i) a[i] = a[i] * mul;
  }
}

// Faithful fp32 port of SSTEQR('I', 3, ...) — verified R7.
__device__ void steqr3f(float* d, float* e, float Z[3][3]) {
#pragma clang fp contract(off)
  const int n = 3;
  const float eps = EPSF, eps2 = EPS2F, safmin = SAFMINF;
  const float ssfmax = sqrtf(SAFMAXF) / 3.0f;
  const float ssfmin = sqrtf(SAFMINF) / EPS2F;
  int jtot = 0; const int nmaxit = n * 30;
  int l1 = 1;

  for (int guard = 0; guard < 200; ++guard) {
    if (l1 > n) break;
    if (l1 > 1) e[l1 - 2] = 0.f;
    int m = n;
    if (l1 <= n - 1) {
      for (int q = l1; q <= n - 1; ++q) {
        float tst = fabsf(e[q - 1]);
        if (tst == 0.f) { m = q; break; }
        if (tst <= (sqrtf(fabsf(d[q - 1])) * sqrtf(fabsf(d[q]))) * eps) { e[q - 1] = 0.f; m = q; break; }
      }
    }
    int l = l1, lsv = l, lend = m, lendsv = lend;
    l1 = m + 1;
    if (lend == l) continue;
    float anorm = 0.f;
    for (int q = l; q <= lend; ++q) anorm = fmaxf(anorm, fabsf(d[q - 1]));
    for (int q = l; q <= lend - 1; ++q) anorm = fmaxf(anorm, fabsf(e[q - 1]));
    int iscale = 0;
    if (anorm == 0.f) continue;
    if (anorm > ssfmax) {
      iscale = 1;
      slascl_g(anorm, ssfmax, lend - l + 1, d + l - 1);
      slascl_g(anorm, ssfmax, lend - l, e + l - 1);
    } else if (anorm < ssfmin) {
      iscale = 2;
      slascl_g(anorm, ssfmin, lend - l + 1, d + l - 1);
      slascl_g(anorm, ssfmin, lend - l, e + l - 1);
    }
    if (fabsf(d[lend - 1]) < fabsf(d[l - 1])) { lend = lsv; l = lendsv; }

    if (lend > l) {
      // QL
      for (int g2 = 0; g2 < 400; ++g2) {
        int mm = lend;
        if (l != lend) {
          bool fnd = false;
          for (int q = l; q <= lend - 1; ++q) {
            float tst = e[q - 1] * e[q - 1];
            if (tst <= (eps2 * fabsf(d[q - 1])) * fabsf(d[q]) + safmin) { mm = q; fnd = true; break; }
          }
          if (!fnd) mm = lend;
        }
        if (mm < lend) e[mm - 1] = 0.f;
        float p = d[l - 1];
        if (mm == l) {
          d[l - 1] = p; ++l;
          if (l <= lend) continue; else break;
        }
        if (mm == l + 1) {
          float rt1, rt2, c, s;
          slaev2f(d[l - 1], e[l - 1], d[l], &rt1, &rt2, &c, &s);
          for (int r2 = 0; r2 < 3; ++r2) {
            float zt = Z[r2][l];
            float zl = Z[r2][l - 1];
            Z[r2][l] = c * zt - s * zl;
            Z[r2][l - 1] = s * zt + c * zl;
          }
          d[l - 1] = rt1; d[l] = rt2; e[l - 1] = 0.f;
          l += 2;
          if (l <= lend) continue; else break;
        }
        if (jtot == nmaxit) break;
        ++jtot;
        float g = (d[l] - p) / (2.0f * e[l - 1]);
        float r = slapy2f(g, 1.0f);
        g = d[mm - 1] - p + e[l - 1] / (g + copysignf(r, g));
        float ss = 1.0f, cc = 1.0f;
        p = 0.f;
        float cw[2], sw[2];
        for (int q = mm - 1; q >= l; --q) {
          float f = ss * e[q - 1];
          float b = cc * e[q - 1];
          float rr;
          slartgf(g, f, &cc, &ss, &rr);
          if (q != mm - 1) e[q] = rr;
          g = d[q] - p;
          rr = (d[q - 1] - g) * ss + 2.0f * cc * b;
          p = ss * rr;
          d[q] = g + p;
          g = cc * rr - b;
          cw[q - l] = cc; sw[q - l] = -ss;
        }
        for (int q = mm - 1; q >= l; --q) {
          float cj = cw[q - l], sj = sw[q - l];
          for (int r2 = 0; r2 < 3; ++r2) {
            float zt = Z[r2][q];
            float zl = Z[r2][q - 1];
            Z[r2][q] = cj * zt - sj * zl;
            Z[r2][q - 1] = sj * zt + cj * zl;
          }
        }
        d[l - 1] = d[l - 1] - p;
        e[l - 1] = g;
      }
    } else {
      // QR
      for (int g2 = 0; g2 < 400; ++g2) {
        int mm = lend;
        if (l != lend) {
          bool fnd = false;
          for (int q = l; q >= lend + 1; --q) {
            float tst = e[q - 2] * e[q - 2];
            if (tst <= (eps2 * fabsf(d[q - 1])) * fabsf(d[q - 2]) + safmin) { mm = q; fnd = true; break; }
          }
          if (!fnd) mm = lend;
        }
        if (mm > lend) e[mm - 2] = 0.f;
        float p = d[l - 1];
        if (mm == l) {
          d[l - 1] = p; --l;
          if (l >= lend) continue; else break;
        }
        if (mm == l - 1) {
          float rt1, rt2, c, s;
          slaev2f(d[l - 2], e[l - 2], d[l - 1], &rt1, &rt2, &c, &s);
          for (int r2 = 0; r2 < 3; ++r2) {
            float zt = Z[r2][l - 1];
            float zl = Z[r2][l - 2];
            Z[r2][l - 1] = c * zt - s * zl;
            Z[r2][l - 2] = s * zt + c * zl;
          }
          d[l - 2] = rt1; d[l - 1] = rt2; e[l - 2] = 0.f;
          l -= 2;
          if (l >= lend) continue; else break;
        }
        if (jtot == nmaxit) break;
        ++jtot;
        float g = (d[l - 2] - p) / (2.0f * e[l - 2]);
        float r = slapy2f(g, 1.0f);
        g = d[mm - 1] - p + e[l - 2] / (g + copysignf(r, g));
        float ss = 1.0f, cc = 1.0f;
        p = 0.f;
        float cw[2], sw[2];
        for (int q = mm; q <= l - 1; ++q) {
          float f = ss * e[q - 1];
          float b = cc * e[q - 1];
          float rr;
          slartgf(g, f, &cc, &ss, &rr);
          if (q != mm) e[q - 2] = rr;
          g = d[q - 1] - p;
          rr = (d[q] - g) * ss + 2.0f * cc * b;
          p = ss * rr;
          d[q - 1] = g + p;
          g = cc * rr - b;
          cw[q - mm] = cc; sw[q - mm] = ss;
        }
        for (int q = mm; q <= l - 1; ++q) {
          float cj = cw[q - mm], sj = sw[q - mm];
          for (int r2 = 0; r2 < 3; ++r2) {
            float zt = Z[r2][q];
            float zl = Z[r2][q - 1];
            Z[r2][q] = cj * zt - sj * zl;
            Z[r2][q - 1] = sj * zt + cj * zl;
          }
        }
        d[l - 1] = d[l - 1] - p;
        e[l - 2] = g;
      }
    }
    if (iscale == 1) {
      slascl_g(ssfmax, anorm, lendsv - lsv + 1, d + lsv - 1);
      slascl_g(ssfmax, anorm, lendsv - lsv, e + lsv - 1);
    } else if (iscale == 2) {
      slascl_g(ssfmin, anorm, lendsv - lsv + 1, d + lsv - 1);
      slascl_g(ssfmin, anorm, lendsv - lsv, e + lsv - 1);
    }
    if (jtot >= nmaxit) break;
  }
  for (int ii = 2; ii <= n; ++ii) {
    int i0 = ii - 1, k0 = i0;
    float p = d[i0 - 1];
    for (int j = ii; j <= n; ++j)
      if (d[j - 1] < p) { k0 = j; p = d[j - 1]; }
    if (k0 != i0) {
      d[k0 - 1] = d[i0 - 1]; d[i0 - 1] = p;
      for (int r2 = 0; r2 < 3; ++r2) {
        float t = Z[r2][i0 - 1]; Z[r2][i0 - 1] = Z[r2][k0 - 1]; Z[r2][k0 - 1] = t;
      }
    }
  }
}

__device__ __forceinline__ float vote5(const float dif[KNN_K][3],
                                       float px, float py, float pz, const float v[3]) {
#pragma clang fp contract(off)
  int cnt = 0;
  for (int k = 0; k < KNN_K; ++k) {
    float w0 = dif[k][0] - px;
    float w1 = dif[k][1] - py;
    float w2 = dif[k][2] - pz;
    float dt = (w0 * v[0] + w1 * v[1]) + w2 * v[2];
    cnt += (dt >= -1e-5f) ? 1 : 0;
  }
  return (2 * cnt >= KNN_K) ? 1.0f : -1.0f;
}

__device__ __forceinline__ void lrf_one(const float* __restrict__ P, float* __restrict__ out,
                                        int i, int n0, int n1, int n2, int n3, int n4) {
#pragma clang fp contract(off)
  int nb[KNN_K] = {n0, n1, n2, n3, n4};
  float px = P[i * 3 + 0], py = P[i * 3 + 1], pz = P[i * 3 + 2];
  float dif[KNN_K][3];
#pragma unroll
  for (int k = 0; k < KNN_K; ++k) {
    int j = nb[k];
    dif[k][0] = P[j * 3 + 0] - px;
    dif[k][1] = P[j * 3 + 1] - py;
    dif[k][2] = P[j * 3 + 2] - pz;
  }
  float mean[3];
  for (int c = 0; c < 3; ++c) {
    float sm = dif[0][c];
    for (int k = 1; k < KNN_K; ++k) sm = sm + dif[k][c];
    mean[c] = sm / 5.0f;
  }
  float cen[KNN_K][3];
  for (int k = 0; k < KNN_K; ++k)
    for (int c = 0; c < 3; ++c) cen[k][c] = dif[k][c] - mean[c];
  float cov[3][3];
  for (int a = 0; a < 3; ++a)
    for (int b = 0; b < 3; ++b) {
      float sm = cen[0][a] * cen[0][b];
      for (int k = 1; k < KNN_K; ++k) sm = sm + cen[k][a] * cen[k][b];
      cov[a][b] = sm / 5.0f;
    }

  float a00 = cov[0][0], a10 = cov[1][0], a20 = cov[2][0];
  float a11 = cov[1][1], a21 = cov[2][1], a22 = cov[2][2];
  float dd[3], ee[2];
  float taui = 0.f, v2 = 0.f;
  float xnorm = fabsf(a20);
  if (xnorm == 0.f) {
    taui = 0.f;
    ee[0] = a10;
    dd[0] = a00; dd[1] = a11; dd[2] = a22; ee[1] = a21;
  } else {
    float beta = -copysignf(slapy2f(a10, xnorm), a10);
    taui = (beta - a10) / beta;
    v2 = a20 * (1.0f / (a10 - beta));
    ee[0] = beta;
    float w1 = taui * a11 + taui * (a21 * v2);
    float w2 = taui * a21 + (taui * v2) * a22;
    float dot = w1 + w2 * v2;
    float al = -((0.5f * taui) * dot);
    w1 = w1 + al;
    w2 = w2 + al * v2;
    dd[1] = (a11 - w1) - w1;
    ee[1] = (a21 - (v2 * w1)) - w2;
    dd[2] = (a22 - (v2 * w2)) - (w2 * v2);
    dd[0] = a00;
  }

  float Zm[3][3] = {{1.f, 0.f, 0.f}, {0.f, 1.f, 0.f}, {0.f, 0.f, 1.f}};
  steqr3f(dd, ee, Zm);

  if (taui != 0.f) {
    for (int j = 0; j < 3; ++j) {
      float w = Zm[1][j] + v2 * Zm[2][j];
      float t = -(taui * w);
      Zm[1][j] = Zm[1][j] + t;
      Zm[2][j] = Zm[2][j] + v2 * t;
    }
  }

  float vx[3] = {Zm[2][0], Zm[2][1], Zm[2][2]};
  float vz[3] = {Zm[0][0], Zm[0][1], Zm[0][2]};
  float sx = vote5(dif, px, py, pz, vx);
  float sz = vote5(dif, px, py, pz, vz);
  float X[3] = {vx[0] * sx, vx[1] * sx, vx[2] * sx};
  float Zx[3] = {vz[0] * sz, vz[1] * sz, vz[2] * sz};
  float Y[3] = {Zx[1] * X[2] - Zx[2] * X[1],
                Zx[2] * X[0] - Zx[0] * X[2],
                Zx[0] * X[1] - Zx[1] * X[0]};
  out[i * 9 + 0] = X[0]; out[i * 9 + 1] = X[1]; out[i * 9 + 2] = X[2];
  out[i * 9 + 3] = Y[0]; out[i * 9 + 4] = Y[1]; out[i * 9 + 5] = Y[2];
  out[i * 9 + 6] = Zx[0]; out[i * 9 + 7] = Zx[1]; out[i * 9 + 8] = Zx[2];
}

// ---- u64 packed key: (monotone-flipped f32 d2) << 32 | idx.
__device__ __forceinline__ unsigned long long packkey(float d, int j) {
  unsigned int b = __float_as_uint(d);
  b ^= (b & 0x80000000u) ? 0xFFFFFFFFu : 0x80000000u;
  return ((unsigned long long)b << 32) | (unsigned int)j;
}

__device__ __forceinline__ float unpackd(unsigned long long k) {
  unsigned int b = (unsigned int)(k >> 32);
  b = (b & 0x80000000u) ? (b ^ 0x80000000u) : ~b;
  return __uint_as_float(b);
}

__device__ __forceinline__ int unpackj(unsigned long long k) {
  return (int)(unsigned int)(k & 0xFFFFFFFFu);
}

// Register-resident top-5 of u64 keys: 5 named scalars, static cascade.
struct Key5 {
  unsigned long long k0, k1, k2, k3, k4;

  __device__ __forceinline__ void init() {
    k0 = k1 = k2 = k3 = k4 = 0xFFFFFFFFFFFFFFFFull;
  }

  __device__ __forceinline__ void insert(unsigned long long k) {
    if (k >= k4) return;
    bool l3 = k < k3;
    bool l2 = k < k2;
    bool l1 = k < k1;
    bool l0 = k < k0;
    k4 = l3 ? k3 : k;
    k3 = l3 ? (l2 ? k2 : k) : k3;
    k2 = l2 ? (l1 ? k1 : k) : k2;
    k1 = l1 ? (l0 ? k0 : k) : k1;
    k0 = l0 ? k : k0;
  }

  __device__ __forceinline__ void merge_xor(int off) {
    unsigned long long p0 = __shfl_xor(k0, off), p1 = __shfl_xor(k1, off),
                       p2 = __shfl_xor(k2, off), p3 = __shfl_xor(k3, off),
                       p4 = __shfl_xor(k4, off);
    insert(p0); insert(p1); insert(p2); insert(p3); insert(p4);
  }
};

// ============================ grid-KNN path ============================

__global__ __launch_bounds__(256) void hist_kernel(
    const float* __restrict__ P, int* __restrict__ counts, int n) {
  int i = blockIdx.x * 256 + threadIdx.x;
  if (i >= n) return;
  int cx = cell1d(P[i * 3 + 0]);
  int cy = cell1d(P[i * 3 + 1]);
  int cz = cell1d(P[i * 3 + 2]);
  atomicAdd(&counts[(cz * GRID + cy) * GRID + cx], 1);
}

__global__ __launch_bounds__(256) void scan_kernel(
    int* __restrict__ counts /* -> offsets[CELLS+1] */,
    int* __restrict__ cursor) {
  __shared__ int psum[256];
  const int tid = threadIdx.x;
  const int CHUNK = CELLS / 256;
  int local[CHUNK];
  int s = 0;
  for (int k = 0; k < CHUNK; ++k) {
    local[k] = s;
    s += counts[tid * CHUNK + k];
  }
  psum[tid] = s;
  __syncthreads();
  for (int off = 1; off < 256; off <<= 1) {
    int v = (tid >= off) ? psum[tid - off] : 0;
    __syncthreads();
    psum[tid] += v;
    __syncthreads();
  }
  int base = (tid > 0) ? psum[tid - 1] : 0;
  for (int k = 0; k < CHUNK; ++k) {
    int o = base + local[k];
    counts[tid * CHUNK + k] = o;
    cursor[tid * CHUNK + k] = o;
  }
  if (tid == 255) counts[CELLS] = psum[255];
}

__global__ __launch_bounds__(256) void scatter_kernel(
    const float* __restrict__ P, int* __restrict__ cursor,
    float4* __restrict__ sorted, int n) {
  int i = blockIdx.x * 256 + threadIdx.x;
  if (i >= n) return;
  float x = P[i * 3 + 0], y = P[i * 3 + 1], z = P[i * 3 + 2];
  int c = (cell1d(z) * GRID + cell1d(y)) * GRID + cell1d(x);
  int pos = atomicAdd(&cursor[c], 1);
  sorted[pos] = make_float4(x, y, z, __int_as_float(i));
}

// KNN (R15 structure + u64 packed keys, R20's best). Writes nbh by sorted pos.
__global__ __launch_bounds__(256) void knn_kernel(
    const float4* __restrict__ sorted, const int* __restrict__ offsets,
    int* __restrict__ nbh, int n) {
  const int tid = threadIdx.x;
  const int r = tid & (LPG - 1);
  const int t = blockIdx.x * (256 / LPG) + (tid / LPG);
  if (t >= n) return;

  float4 q = sorted[t];
  const float qs = sqnorm3(q.x, q.y, q.z);
  const int cx = cell1d(q.x), cy = cell1d(q.y), cz = cell1d(q.z);
  const float h = 1.0f / (float)GRID;

  Key5 tp;
  tp.init();

  // ---- Ring 0..1: 9 row-spans, descriptors prefetched (MLP) ----
  {
    const int x0 = max(0, cx - 1), x1 = min(GRID - 1, cx + 1);
    const int xsp = x1 - x0 + 1;
    int ksv[9], kev[9];
#pragma unroll
    for (int s9 = 0; s9 < 9; ++s9) {
      int dz = s9 / 3 - 1, dy = s9 % 3 - 1;
      int zz = cz + dz, yy = cy + dy;
      bool ok = (zz >= 0) && (zz < GRID) && (yy >= 0) && (yy < GRID);
      int c0 = ok ? ((zz * GRID + yy) * GRID + x0) : 0;
      int ks = offsets[c0];
      int ke = offsets[c0 + xsp];
      ksv[s9] = ks;
      kev[s9] = ok ? ke : ks;
    }
#pragma unroll
    for (int s9 = 0; s9 < 9; ++s9) {
      for (int k = ksv[s9] + r; k < kev[s9]; k += LPG) {
        float4 p = sorted[k];
        float psq = sqnorm3(p.x, p.y, p.z);
        float dv = dist2(q.x, q.y, q.z, qs, p.x, p.y, p.z, psq);
        tp.insert(packkey(dv, __float_as_int(p.w)));
      }
    }
  }

  // group-min bound (conservative, sound)
  float B = unpackd(tp.k4);
  B = fminf(B, __shfl_xor(B, 1));
  B = fminf(B, __shfl_xor(B, 2));
  B = fminf(B, __shfl_xor(B, 4));

  // Rings m>=2 (boundary-point tail; striped within contiguous spans).
  for (int m = 2; m < GRID; ++m) {
    float lb = (float)(m - 1) * h;
    if (lb * lb > B * 1.00001f + 1e-6f) break;
    for (int dz = -m; dz <= m; ++dz) {
      int zz = cz + dz;
      if (zz < 0 || zz >= GRID) continue;
      bool zface = (dz == -m || dz == m);
      for (int dy = -m; dy <= m; ++dy) {
        int yy = cy + dy;
        if (yy < 0 || yy >= GRID) continue;
        bool yface = (dy == -m || dy == m);
        int rowbase = (zz * GRID + yy) * GRID;
        if (zface || yface) {
          int x0 = max(0, cx - m), x1 = min(GRID - 1, cx + m);
          int ks = offsets[rowbase + x0], ke = offsets[rowbase + x1 + 1];
          for (int k = ks + r; k < ke; k += LPG) {
            float4 p = sorted[k];
            float psq = sqnorm3(p.x, p.y, p.z);
            float dv = dist2(q.x, q.y, q.z, qs, p.x, p.y, p.z, psq);
            tp.insert(packkey(dv, __float_as_int(p.w)));
          }
        } else {
          int xa = cx - m, xb = cx + m;
          if (xa >= 0) {
            int ks = offsets[rowbase + xa], ke = offsets[rowbase + xa + 1];
            for (int k = ks + r; k < ke; k += LPG) {
              float4 p = sorted[k];
              float psq = sqnorm3(p.x, p.y, p.z);
              float dv = dist2(q.x, q.y, q.z, qs, p.x, p.y, p.z, psq);
              tp.insert(packkey(dv, __float_as_int(p.w)));
            }
          }
          if (xb < GRID) {
            int ks = offsets[rowbase + xb], ke = offsets[rowbase + xb + 1];
            for (int k = ks + r; k < ke; k += LPG) {
              float4 p = sorted[k];
              float psq = sqnorm3(p.x, p.y, p.z);
              float dv = dist2(q.x, q.y, q.z, qs, p.x, p.y, p.z, psq);
              tp.insert(packkey(dv, __float_as_int(p.w)));
            }
          }
        }
      }
    }
    B = unpackd(tp.k4);
    B = fminf(B, __shfl_xor(B, 1));
    B = fminf(B, __shfl_xor(B, 2));
    B = fminf(B, __shfl_xor(B, 4));
  }

  // exact final merge of the 8 disjoint per-lane lists
  tp.merge_xor(1);
  tp.merge_xor(2);
  tp.merge_xor(4);

  if (r == 0) {
    nbh[t * 5 + 0] = unpackj(tp.k0);
    nbh[t * 5 + 1] = unpackj(tp.k1);
    nbh[t * 5 + 2] = unpackj(tp.k2);
    nbh[t * 5 + 3] = unpackj(tp.k3);
    nbh[t * 5 + 4] = unpackj(tp.k4);
  }
}

// Solver: 1 thread/point in sorted order, but launched as 512-thread blocks
// (8 waves/block, 32 blocks) so each SIMD has 2 co-resident waves whose
// independent dependency chains fill each other's stall slots.
// (Old 64-thread/256-block launch: 1 wave/CU, 0.25 waves/SIMD, 40us at
// VALUBusy 6.6% -- pure unhidden fp32-chain latency.)
__global__ __launch_bounds__(SOLVER_TPB) void solver_kernel(
    const float* __restrict__ P, const float4* __restrict__ sorted,
    const int* __restrict__ nbh, float* __restrict__ out, int n) {
  for (int t = blockIdx.x * SOLVER_TPB + threadIdx.x; t < n;
       t += gridDim.x * SOLVER_TPB) {
    int io = __float_as_int(sorted[t].w);
    lrf_one(P, out, io,
            nbh[t * 5 + 0], nbh[t * 5 + 1], nbh[t * 5 + 2],
            nbh[t * 5 + 3], nbh[t * 5 + 4]);
  }
}

// ======================= brute-force fallback =======================

__global__ __launch_bounds__(TPB) void knn_brute_kernel(
    const float* __restrict__ P, float* __restrict__ out, int n) {
  __shared__ float4 tile[TILE];

  const int tid = threadIdx.x;
  const int p = tid >> 4;
  const int s = tid & 15;
  const int i = blockIdx.x * PPB + p;
  const int iq = (i < n) ? i : (n - 1);

  const float qx = P[iq * 3 + 0];
  const float qy = P[iq * 3 + 1];
  const float qz = P[iq * 3 + 2];
  const float qs = sqnorm3(qx, qy, qz);

  Key5 t;
  t.init();

  for (int base = 0; base < n; base += TILE) {
    int cnt = min(TILE, n - base);
    __syncthreads();
    for (int j = tid; j < cnt; j += TPB) {
      float x = P[(base + j) * 3 + 0];
      float y = P[(base + j) * 3 + 1];
      float z = P[(base + j) * 3 + 2];
      tile[j] = make_float4(x, y, z, sqnorm3(x, y, z));
    }
    __syncthreads();
    for (int j = s; j < cnt; j += STR) {
      float4 q = tile[j];
      t.insert(packkey(dist2(qx, qy, qz, qs, q.x, q.y, q.z, q.w), base + j));
    }
  }

#pragma unroll
  for (int rnd = 0; rnd < 4; ++rnd) {
    t.merge_xor(1 << rnd);
  }

  if (s == 0 && i < n) {
    lrf_one(P, out, i, unpackj(t.k0), unpackj(t.k1), unpackj(t.k2),
            unpackj(t.k3), unpackj(t.k4));
  }
}

}  // namespace

extern "C" void kernel_launch(void* const* d_in, const int* in_sizes, int n_in,
                              void* d_out, int out_size, void* d_ws, size_t ws_size,
                              hipStream_t stream) {
  (void)n_in; (void)out_size;
  const float* P = (const float*)d_in[0];
  float* out = (float*)d_out;
  const int n = in_sizes[0] / 3;
  if (n <= 0) return;

  // Workspace: sorted f4[n] | offsets int[CELLS+1] | cursor int[CELLS] | nbh int[5n]
  size_t off_sorted = 0;
  size_t off_counts = off_sorted + (size_t)n * sizeof(float4);
  size_t off_cursor = off_counts + ((size_t)(CELLS + 1) * sizeof(int) + 15) / 16 * 16;
  size_t off_nbh = off_cursor + (size_t)CELLS * sizeof(int);
  size_t need = off_nbh + (size_t)n * 5 * sizeof(int);

  if (ws_size >= need && n >= KNN_K) {
    char* base = (char*)d_ws;
    float4* sorted = (float4*)(base + off_sorted);
    int* counts = (int*)(base + off_counts);
    int* cursor = (int*)(base + off_cursor);
    int* nbh = (int*)(base + off_nbh);

    hipMemsetAsync(counts, 0, (size_t)CELLS * sizeof(int), stream);
    hist_kernel<<<(n + 255) / 256, 256, 0, stream>>>(P, counts, n);
    scan_kernel<<<1, 256, 0, stream>>>(counts, cursor);
    scatter_kernel<<<(n + 255) / 256, 256, 0, stream>>>(P, cursor, sorted, n);
    const int ppb = 256 / LPG;  // 32 points per block
    knn_kernel<<<(n + ppb - 1) / ppb, 256, 0, stream>>>(sorted, counts, nbh, n);
    const int sblocks = (n + SOLVER_TPB - 1) / SOLVER_TPB;  // 32 blocks @ n=16384
    solver_kernel<<<sblocks, SOLVER_TPB, 0, stream>>>(P, sorted, nbh, out, n);
  } else {
    const int blocks = (n + PPB - 1) / PPB;
    knn_brute_kernel<<<blocks, TPB, 0, stream>>>(P, out, n);
  }
}

// Round 23
// 90.961 us; speedup vs baseline: 1.0732x; 1.0732x over previous
//
#include <hip/hip_runtime.h>

// LAPACK slartg vintage: 1 = LAPACK >= 3.10
#define SLARTG_NEW 1

namespace {

constexpr int KNN_K = 5;
constexpr int GRID = 16;                 // cells per axis; h = 1/16
constexpr int CELLS = GRID * GRID * GRID;
constexpr int LPG = 8;                   // lanes per point (KNN kernel)

// Brute-force fallback config
constexpr int PPB = 16;
constexpr int STR = 16;
constexpr int TPB = PPB * STR;
constexpr int TILE = 2048;

// fp32 LAPACK machine constants (exact IEEE-single values)
#define EPSF    5.9604644775390625e-8f
#define EPS2F   3.552713678800501e-15f
#define SAFMINF 1.1754943508222875e-38f
#define SAFMAXF 8.507059173023462e+37f
#define RTMINF  1.0842021724855044e-19f
#define RTMAXF  9.223372036854776e+18f

// ---- fp32 helpers: ALL-PLAIN rounding (no-FMA reference stack, verified R7) ----
__device__ __forceinline__ float sqnorm3(float x, float y, float z) {
#pragma clang fp contract(off)
  float a = x * x;
  float b = y * y;
  float c = z * z;
  return (a + b) + c;
}

__device__ __forceinline__ float dist2(float xi, float yi, float zi, float sqi,
                                       float xj, float yj, float zj, float sqj) {
#pragma clang fp contract(off)
  float dot = (xi * xj + yi * yj) + zi * zj; // PLAIN, no FMA — verified R7
  float a = sqi + sqj;
  return a - 2.0f * dot;
}

__device__ __forceinline__ int cell1d(float v) {
  int c = (int)(v * (float)GRID);
  if (c < 0) c = 0;
  if (c > GRID - 1) c = GRID - 1;
  return c;
}

// ---- fp32 LAPACK ports (reference netlib, plain rounding) — verified R7 ----
__device__ __forceinline__ float slapy2f(float x, float y) {
#pragma clang fp contract(off)
  float xa = fabsf(x), ya = fabsf(y);
  float w = fmaxf(xa, ya);
  float z = fminf(xa, ya);
  if (z == 0.f) return w;
  float q = z / w;
  float q2 = q * q;
  float s = 1.0f + q2;
  return w * sqrtf(s);
}

__device__ __forceinline__ void slartgf(float f, float g, float* cs, float* sn, float* r) {
#pragma clang fp contract(off)
#if SLARTG_NEW
  float f1 = fabsf(f), g1 = fabsf(g);
  if (g == 0.f) { *cs = 1.f; *sn = 0.f; *r = f; }
  else if (f == 0.f) { *cs = 0.f; *sn = copysignf(1.f, g); *r = g1; }
  else if (f1 > RTMINF && f1 < RTMAXF && g1 > RTMINF && g1 < RTMAXF) {
    float ff = f * f;
    float gg = g * g;
    float d = sqrtf(ff + gg);
    *cs = f1 / d;
    float rr = copysignf(d, f);
    *sn = g / rr;
    *r = rr;
  } else {
    float u = fminf(SAFMAXF, fmaxf(fmaxf(SAFMINF, f1), g1));
    float fs = f / u, gs = g / u;
    float ff = fs * fs;
    float gg = gs * gs;
    float d = sqrtf(ff + gg);
    *cs = fabsf(fs) / d;
    float rr = copysignf(d, f);
    *sn = gs / rr;
    *r = rr * u;
  }
#else
  if (g == 0.f) { *cs = 1.f; *sn = 0.f; *r = f; }
  else if (f == 0.f) { *cs = 0.f; *sn = 1.f; *r = g; }
  else {
    float f2 = f * f;
    float g2 = g * g;
    float rr = sqrtf(f2 + g2);
    float c = f / rr, s = g / rr;
    if (fabsf(f) > fabsf(g) && c < 0.f) { c = -c; s = -s; rr = -rr; }
    *cs = c; *sn = s; *r = rr;
  }
#endif
}

__device__ __forceinline__ void slaev2f(float a, float b, float c,
                                        float* rt1, float* rt2, float* cs1, float* sn1) {
#pragma clang fp contract(off)
  float sm = a + c;
  float df = a - c;
  float adf = fabsf(df);
  float tb = b + b;
  float ab = fabsf(tb);
  float acmx, acmn;
  if (fabsf(a) > fabsf(c)) { acmx = a; acmn = c; } else { acmx = c; acmn = a; }
  float rt;
  if (adf > ab) { float q = ab / adf; rt = adf * sqrtf(1.0f + q * q); }
  else if (adf < ab) { float q = adf / ab; rt = ab * sqrtf(1.0f + q * q); }
  else rt = ab * sqrtf(2.0f);
  int sgn1;
  if (sm < 0.f) { *rt1 = 0.5f * (sm - rt); sgn1 = -1; *rt2 = (acmx / *rt1) * acmn - (b / *rt1) * b; }
  else if (sm > 0.f) { *rt1 = 0.5f * (sm + rt); sgn1 = 1; *rt2 = (acmx / *rt1) * acmn - (b / *rt1) * b; }
  else { *rt1 = 0.5f * rt; *rt2 = -0.5f * rt; sgn1 = 1; }
  float cs; int sgn2;
  if (df >= 0.f) { cs = df + rt; sgn2 = 1; } else { cs = df - rt; sgn2 = -1; }
  float acs = fabsf(cs);
  float c1, s1;
  if (acs > ab) {
    float ct = -tb / cs;
    s1 = 1.0f / sqrtf(1.0f + ct * ct);
    c1 = ct * s1;
  } else {
    if (ab == 0.f) { c1 = 1.f; s1 = 0.f; }
    else {
      float tn = -cs / tb;
      c1 = 1.0f / sqrtf(1.0f + tn * tn);
      s1 = tn * c1;
    }
  }
  if (sgn1 == sgn2) { float tn = c1; c1 = -s1; s1 = tn; }
  *cs1 = c1; *sn1 = s1;
}

__device__ __forceinline__ void slascl_g(float cfrom, float cto, int n, float* a) {
#pragma clang fp contract(off)
  float cfromc = cfrom, ctoc = cto;
  bool done = false;
  int guard = 0;
  while (!done && guard++ < 50) {
    float mul;
    float cfrom1 = cfromc * SAFMINF;
    if (cfrom1 == cfromc) {
      mul = ctoc / cfromc; done = true;
    } else {
      float cto1 = ctoc / SAFMAXF;
      if (cto1 == ctoc) { mul = ctoc; done = true; cfromc = 1.f; }
      else if (fabsf(cfrom1) > fabsf(ctoc) && ctoc != 0.f) { mul = SAFMINF; done = false; cfromc = cfrom1; }
      else if (fabsf(cto1) > fabsf(cfromc)) { mul = SAFMAXF; done = false; ctoc = cto1; }
      else { mul = ctoc / cfromc; done = true; }
    }
    for (int i = 0; i < n; ++i) a[i] = a[i] * mul;
  }
}

// Faithful fp32 port of SSTEQR('I', 3, ...) — verified R7.
__device__ void steqr3f(float* d, float* e, float Z[3][3]) {
#pragma clang fp contract(off)
  const int n = 3;
  const float eps = EPSF, eps2 = EPS2F, safmin = SAFMINF;
  const float ssfmax = sqrtf(SAFMAXF) / 3.0f;
  const float ssfmin = sqrtf(SAFMINF) / EPS2F;
  int jtot = 0; const int nmaxit = n * 30;
  int l1 = 1;

  for (int guard = 0; guard < 200; ++guard) {
    if (l1 > n) break;
    if (l1 > 1) e[l1 - 2] = 0.f;
    int m = n;
    if (l1 <= n - 1) {
      for (int q = l1; q <= n - 1; ++q) {
        float tst = fabsf(e[q - 1]);
        if (tst == 0.f) { m = q; break; }
        if (tst <= (sqrtf(fabsf(d[q - 1])) * sqrtf(fabsf(d[q]))) * eps) { e[q - 1] = 0.f; m = q; break; }
      }
    }
    int l = l1, lsv = l, lend = m, lendsv = lend;
    l1 = m + 1;
    if (lend == l) continue;
    float anorm = 0.f;
    for (int q = l; q <= lend; ++q) anorm = fmaxf(anorm, fabsf(d[q - 1]));
    for (int q = l; q <= lend - 1; ++q) anorm = fmaxf(anorm, fabsf(e[q - 1]));
    int iscale = 0;
    if (anorm == 0.f) continue;
    if (anorm > ssfmax) {
      iscale = 1;
      slascl_g(anorm, ssfmax, lend - l + 1, d + l - 1);
      slascl_g(anorm, ssfmax, lend - l, e + l - 1);
    } else if (anorm < ssfmin) {
      iscale = 2;
      slascl_g(anorm, ssfmin, lend - l + 1, d + l - 1);
      slascl_g(anorm, ssfmin, lend - l, e + l - 1);
    }
    if (fabsf(d[lend - 1]) < fabsf(d[l - 1])) { lend = lsv; l = lendsv; }

    if (lend > l) {
      // QL
      for (int g2 = 0; g2 < 400; ++g2) {
        int mm = lend;
        if (l != lend) {
          bool fnd = false;
          for (int q = l; q <= lend - 1; ++q) {
            float tst = e[q - 1] * e[q - 1];
            if (tst <= (eps2 * fabsf(d[q - 1])) * fabsf(d[q]) + safmin) { mm = q; fnd = true; break; }
          }
          if (!fnd) mm = lend;
        }
        if (mm < lend) e[mm - 1] = 0.f;
        float p = d[l - 1];
        if (mm == l) {
          d[l - 1] = p; ++l;
          if (l <= lend) continue; else break;
        }
        if (mm == l + 1) {
          float rt1, rt2, c, s;
          slaev2f(d[l - 1], e[l - 1], d[l], &rt1, &rt2, &c, &s);
          for (int r2 = 0; r2 < 3; ++r2) {
            float zt = Z[r2][l];
            float zl = Z[r2][l - 1];
            Z[r2][l] = c * zt - s * zl;
            Z[r2][l - 1] = s * zt + c * zl;
          }
          d[l - 1] = rt1; d[l] = rt2; e[l - 1] = 0.f;
          l += 2;
          if (l <= lend) continue; else break;
        }
        if (jtot == nmaxit) break;
        ++jtot;
        float g = (d[l] - p) / (2.0f * e[l - 1]);
        float r = slapy2f(g, 1.0f);
        g = d[mm - 1] - p + e[l - 1] / (g + copysignf(r, g));
        float ss = 1.0f, cc = 1.0f;
        p = 0.f;
        float cw[2], sw[2];
        for (int q = mm - 1; q >= l; --q) {
          float f = ss * e[q - 1];
          float b = cc * e[q - 1];
          float rr;
          slartgf(g, f, &cc, &ss, &rr);
          if (q != mm - 1) e[q] = rr;
          g = d[q] - p;
          rr = (d[q - 1] - g) * ss + 2.0f * cc * b;
          p = ss * rr;
          d[q] = g + p;
          g = cc * rr - b;
          cw[q - l] = cc; sw[q - l] = -ss;
        }
        for (int q = mm - 1; q >= l; --q) {
          float cj = cw[q - l], sj = sw[q - l];
          for (int r2 = 0; r2 < 3; ++r2) {
            float zt = Z[r2][q];
            float zl = Z[r2][q - 1];
            Z[r2][q] = cj * zt - sj * zl;
            Z[r2][q - 1] = sj * zt + cj * zl;
          }
        }
        d[l - 1] = d[l - 1] - p;
        e[l - 1] = g;
      }
    } else {
      // QR
      for (int g2 = 0; g2 < 400; ++g2) {
        int mm = lend;
        if (l != lend) {
          bool fnd = false;
          for (int q = l; q >= lend + 1; --q) {
            float tst = e[q - 2] * e[q - 2];
            if (tst <= (eps2 * fabsf(d[q - 1])) * fabsf(d[q - 2]) + safmin) { mm = q; fnd = true; break; }
          }
          if (!fnd) mm = lend;
        }
        if (mm > lend) e[mm - 2] = 0.f;
        float p = d[l - 1];
        if (mm == l) {
          d[l - 1] = p; --l;
          if (l >= lend) continue; else break;
        }
        if (mm == l - 1) {
          float rt1, rt2, c, s;
          slaev2f(d[l - 2], e[l - 2], d[l - 1], &rt1, &rt2, &c, &s);
          for (int r2 = 0; r2 < 3; ++r2) {
            float zt = Z[r2][l - 1];
            float zl = Z[r2][l - 2];
            Z[r2][l - 1] = c * zt - s * zl;
            Z[r2][l - 2] = s * zt + c * zl;
          }
          d[l - 2] = rt1; d[l - 1] = rt2; e[l - 2] = 0.f;
          l -= 2;
          if (l >= lend) continue; else break;
        }
        if (jtot == nmaxit) break;
        ++jtot;
        float g = (d[l - 2] - p) / (2.0f * e[l - 2]);
        float r = slapy2f(g, 1.0f);
        g = d[mm - 1] - p + e[l - 2] / (g + copysignf(r, g));
        float ss = 1.0f, cc = 1.0f;
        p = 0.f;
        float cw[2], sw[2];
        for (int q = mm; q <= l - 1; ++q) {
          float f = ss * e[q - 1];
          float b = cc * e[q - 1];
          float rr;
          slartgf(g, f, &cc, &ss, &rr);
          if (q != mm) e[q - 2] = rr;
          g = d[q - 1] - p;
          rr = (d[q] - g) * ss + 2.0f * cc * b;
          p = ss * rr;
          d[q - 1] = g + p;
          g = cc * rr - b;
          cw[q - mm] = cc; sw[q - mm] = ss;
        }
        for (int q = mm; q <= l - 1; ++q) {
          float cj = cw[q - mm], sj = sw[q - mm];
          for (int r2 = 0; r2 < 3; ++r2) {
            float zt = Z[r2][q];
            float zl = Z[r2][q - 1];
            Z[r2][q] = cj * zt - sj * zl;
            Z[r2][q - 1] = sj * zt + cj * zl;
          }
        }
        d[l - 1] = d[l - 1] - p;
        e[l - 2] = g;
      }
    }
    if (iscale == 1) {
      slascl_g(ssfmax, anorm, lendsv - lsv + 1, d + lsv - 1);
      slascl_g(ssfmax, anorm, lendsv - lsv, e + lsv - 1);
    } else if (iscale == 2) {
      slascl_g(ssfmin, anorm, lendsv - lsv + 1, d + lsv - 1);
      slascl_g(ssfmin, anorm, lendsv - lsv, e + lsv - 1);
    }
    if (jtot >= nmaxit) break;
  }
  for (int ii = 2; ii <= n; ++ii) {
    int i0 = ii - 1, k0 = i0;
    float p = d[i0 - 1];
    for (int j = ii; j <= n; ++j)
      if (d[j - 1] < p) { k0 = j; p = d[j - 1]; }
    if (k0 != i0) {
      d[k0 - 1] = d[i0 - 1]; d[i0 - 1] = p;
      for (int r2 = 0; r2 < 3; ++r2) {
        float t = Z[r2][i0 - 1]; Z[r2][i0 - 1] = Z[r2][k0 - 1]; Z[r2][k0 - 1] = t;
      }
    }
  }
}

// Compute cov -> tridiag (dd, ee) + taui, v2 — shared by solver and classify.
__device__ __forceinline__ void tridiag_of(const float* __restrict__ P, int i,
                                           const int* nb, float dif[KNN_K][3],
                                           float dd[3], float ee[2],
                                           float* taui_o, float* v2_o) {
#pragma clang fp contract(off)
  float px = P[i * 3 + 0], py = P[i * 3 + 1], pz = P[i * 3 + 2];
#pragma unroll
  for (int k = 0; k < KNN_K; ++k) {
    int j = nb[k];
    dif[k][0] = P[j * 3 + 0] - px;
    dif[k][1] = P[j * 3 + 1] - py;
    dif[k][2] = P[j * 3 + 2] - pz;
  }
  float mean[3];
  for (int c = 0; c < 3; ++c) {
    float sm = dif[0][c];
    for (int k = 1; k < KNN_K; ++k) sm = sm + dif[k][c];
    mean[c] = sm / 5.0f;
  }
  float cen[KNN_K][3];
  for (int k = 0; k < KNN_K; ++k)
    for (int c = 0; c < 3; ++c) cen[k][c] = dif[k][c] - mean[c];
  float cov[3][3];
  for (int a = 0; a < 3; ++a)
    for (int b = 0; b < 3; ++b) {
      float sm = cen[0][a] * cen[0][b];
      for (int k = 1; k < KNN_K; ++k) sm = sm + cen[k][a] * cen[k][b];
      cov[a][b] = sm / 5.0f;
    }

  float a00 = cov[0][0], a10 = cov[1][0], a20 = cov[2][0];
  float a11 = cov[1][1], a21 = cov[2][1], a22 = cov[2][2];
  float taui = 0.f, v2 = 0.f;
  float xnorm = fabsf(a20);
  if (xnorm == 0.f) {
    taui = 0.f;
    ee[0] = a10;
    dd[0] = a00; dd[1] = a11; dd[2] = a22; ee[1] = a21;
  } else {
    float beta = -copysignf(slapy2f(a10, xnorm), a10);
    taui = (beta - a10) / beta;
    v2 = a20 * (1.0f / (a10 - beta));
    ee[0] = beta;
    float w1 = taui * a11 + taui * (a21 * v2);
    float w2 = taui * a21 + (taui * v2) * a22;
    float dot = w1 + w2 * v2;
    float al = -((0.5f * taui) * dot);
    w1 = w1 + al;
    w2 = w2 + al * v2;
    dd[1] = (a11 - w1) - w1;
    ee[1] = (a21 - (v2 * w1)) - w2;
    dd[2] = (a22 - (v2 * w2)) - (w2 * v2);
    dd[0] = a00;
  }
  *taui_o = taui;
  *v2_o = v2;
}

__device__ __forceinline__ float vote5(const float dif[KNN_K][3],
                                       float px, float py, float pz, const float v[3]) {
#pragma clang fp contract(off)
  int cnt = 0;
  for (int k = 0; k < KNN_K; ++k) {
    float w0 = dif[k][0] - px;
    float w1 = dif[k][1] - py;
    float w2 = dif[k][2] - pz;
    float dt = (w0 * v[0] + w1 * v[1]) + w2 * v[2];
    cnt += (dt >= -1e-5f) ? 1 : 0;
  }
  return (2 * cnt >= KNN_K) ? 1.0f : -1.0f;
}

__device__ __forceinline__ void lrf_one(const float* __restrict__ P, float* __restrict__ out,
                                        int i, int n0, int n1, int n2, int n3, int n4) {
#pragma clang fp contract(off)
  int nb[KNN_K] = {n0, n1, n2, n3, n4};
  float dif[KNN_K][3];
  float dd[3], ee3[3];
  float taui, v2;
  tridiag_of(P, i, nb, dif, dd, ee3, &taui, &v2);
  ee3[2] = 0.f;

  float Zm[3][3] = {{1.f, 0.f, 0.f}, {0.f, 1.f, 0.f}, {0.f, 0.f, 1.f}};
  steqr3f(dd, ee3, Zm);

  if (taui != 0.f) {
    for (int j = 0; j < 3; ++j) {
      float w = Zm[1][j] + v2 * Zm[2][j];
      float t = -(taui * w);
      Zm[1][j] = Zm[1][j] + t;
      Zm[2][j] = Zm[2][j] + v2 * t;
    }
  }

  float px = P[i * 3 + 0], py = P[i * 3 + 1], pz = P[i * 3 + 2];
  float vx[3] = {Zm[2][0], Zm[2][1], Zm[2][2]};
  float vz[3] = {Zm[0][0], Zm[0][1], Zm[0][2]};
  float sx = vote5(dif, px, py, pz, vx);
  float sz = vote5(dif, px, py, pz, vz);
  float X[3] = {vx[0] * sx, vx[1] * sx, vx[2] * sx};
  float Zx[3] = {vz[0] * sz, vz[1] * sz, vz[2] * sz};
  float Y[3] = {Zx[1] * X[2] - Zx[2] * X[1],
                Zx[2] * X[0] - Zx[0] * X[2],
                Zx[0] * X[1] - Zx[1] * X[0]};
  out[i * 9 + 0] = X[0]; out[i * 9 + 1] = X[1]; out[i * 9 + 2] = X[2];
  out[i * 9 + 3] = Y[0]; out[i * 9 + 4] = Y[1]; out[i * 9 + 5] = Y[2];
  out[i * 9 + 6] = Zx[0]; out[i * 9 + 7] = Zx[1]; out[i * 9 + 8] = Zx[2];
}

// ---- u64 packed key: (monotone-flipped f32 d2) << 32 | idx.
__device__ __forceinline__ unsigned long long packkey(float d, int j) {
  unsigned int b = __float_as_uint(d);
  b ^= (b & 0x80000000u) ? 0xFFFFFFFFu : 0x80000000u;
  return ((unsigned long long)b << 32) | (unsigned int)j;
}

__device__ __forceinline__ float unpackd(unsigned long long k) {
  unsigned int b = (unsigned int)(k >> 32);
  b = (b & 0x80000000u) ? (b ^ 0x80000000u) : ~b;
  return __uint_as_float(b);
}

__device__ __forceinline__ int unpackj(unsigned long long k) {
  return (int)(unsigned int)(k & 0xFFFFFFFFu);
}

// Register-resident top-5 of u64 keys: 5 named scalars, static cascade.
struct Key5 {
  unsigned long long k0, k1, k2, k3, k4;

  __device__ __forceinline__ void init() {
    k0 = k1 = k2 = k3 = k4 = 0xFFFFFFFFFFFFFFFFull;
  }

  __device__ __forceinline__ void insert(unsigned long long k) {
    if (k >= k4) return;
    bool l3 = k < k3;
    bool l2 = k < k2;
    bool l1 = k < k1;
    bool l0 = k < k0;
    k4 = l3 ? k3 : k;
    k3 = l3 ? (l2 ? k2 : k) : k3;
    k2 = l2 ? (l1 ? k1 : k) : k2;
    k1 = l1 ? (l0 ? k0 : k) : k1;
    k0 = l0 ? k : k0;
  }

  __device__ __forceinline__ void merge_xor(int off) {
    unsigned long long p0 = __shfl_xor(k0, off), p1 = __shfl_xor(k1, off),
                       p2 = __shfl_xor(k2, off), p3 = __shfl_xor(k3, off),
                       p4 = __shfl_xor(k4, off);
    insert(p0); insert(p1); insert(p2); insert(p3); insert(p4);
  }
};

// ============================ grid-KNN path ============================

__global__ __launch_bounds__(256) void hist_kernel(
    const float* __restrict__ P, int* __restrict__ counts, int n) {
  int i = blockIdx.x * 256 + threadIdx.x;
  if (i >= n) return;
  int cx = cell1d(P[i * 3 + 0]);
  int cy = cell1d(P[i * 3 + 1]);
  int cz = cell1d(P[i * 3 + 2]);
  atomicAdd(&counts[(cz * GRID + cy) * GRID + cx], 1);
}

__global__ __launch_bounds__(256) void scan_kernel(
    int* __restrict__ counts /* -> offsets[CELLS+1] */,
    int* __restrict__ cursor) {
  __shared__ int psum[256];
  const int tid = threadIdx.x;
  const int CHUNK = CELLS / 256;
  int local[CHUNK];
  int s = 0;
  for (int k = 0; k < CHUNK; ++k) {
    local[k] = s;
    s += counts[tid * CHUNK + k];
  }
  psum[tid] = s;
  __syncthreads();
  for (int off = 1; off < 256; off <<= 1) {
    int v = (tid >= off) ? psum[tid - off] : 0;
    __syncthreads();
    psum[tid] += v;
    __syncthreads();
  }
  int base = (tid > 0) ? psum[tid - 1] : 0;
  for (int k = 0; k < CHUNK; ++k) {
    int o = base + local[k];
    counts[tid * CHUNK + k] = o;
    cursor[tid * CHUNK + k] = o;
  }
  if (tid == 255) counts[CELLS] = psum[255];
}

__global__ __launch_bounds__(256) void scatter_kernel(
    const float* __restrict__ P, int* __restrict__ cursor,
    float4* __restrict__ sorted, int n) {
  int i = blockIdx.x * 256 + threadIdx.x;
  if (i >= n) return;
  float x = P[i * 3 + 0], y = P[i * 3 + 1], z = P[i * 3 + 2];
  int c = (cell1d(z) * GRID + cell1d(y)) * GRID + cell1d(x);
  int pos = atomicAdd(&cursor[c], 1);
  sorted[pos] = make_float4(x, y, z, __int_as_float(i));
}

// KNN (R20's best: R15 structure + u64 packed keys). Writes nbh by sorted pos.
__global__ __launch_bounds__(256) void knn_kernel(
    const float4* __restrict__ sorted, const int* __restrict__ offsets,
    int* __restrict__ nbh, int n) {
  const int tid = threadIdx.x;
  const int r = tid & (LPG - 1);
  const int t = blockIdx.x * (256 / LPG) + (tid / LPG);
  if (t >= n) return;

  float4 q = sorted[t];
  const float qs = sqnorm3(q.x, q.y, q.z);
  const int cx = cell1d(q.x), cy = cell1d(q.y), cz = cell1d(q.z);
  const float h = 1.0f / (float)GRID;

  Key5 tp;
  tp.init();

  // ---- Ring 0..1: 9 row-spans, descriptors prefetched (MLP) ----
  {
    const int x0 = max(0, cx - 1), x1 = min(GRID - 1, cx + 1);
    const int xsp = x1 - x0 + 1;
    int ksv[9], kev[9];
#pragma unroll
    for (int s9 = 0; s9 < 9; ++s9) {
      int dz = s9 / 3 - 1, dy = s9 % 3 - 1;
      int zz = cz + dz, yy = cy + dy;
      bool ok = (zz >= 0) && (zz < GRID) && (yy >= 0) && (yy < GRID);
      int c0 = ok ? ((zz * GRID + yy) * GRID + x0) : 0;
      int ks = offsets[c0];
      int ke = offsets[c0 + xsp];
      ksv[s9] = ks;
      kev[s9] = ok ? ke : ks;
    }
#pragma unroll
    for (int s9 = 0; s9 < 9; ++s9) {
      for (int k = ksv[s9] + r; k < kev[s9]; k += LPG) {
        float4 p = sorted[k];
        float psq = sqnorm3(p.x, p.y, p.z);
        float dv = dist2(q.x, q.y, q.z, qs, p.x, p.y, p.z, psq);
        tp.insert(packkey(dv, __float_as_int(p.w)));
      }
    }
  }

  // group-min bound (conservative, sound)
  float B = unpackd(tp.k4);
  B = fminf(B, __shfl_xor(B, 1));
  B = fminf(B, __shfl_xor(B, 2));
  B = fminf(B, __shfl_xor(B, 4));

  // Rings m>=2 (boundary-point tail; striped within contiguous spans).
  for (int m = 2; m < GRID; ++m) {
    float lb = (float)(m - 1) * h;
    if (lb * lb > B * 1.00001f + 1e-6f) break;
    for (int dz = -m; dz <= m; ++dz) {
      int zz = cz + dz;
      if (zz < 0 || zz >= GRID) continue;
      bool zface = (dz == -m || dz == m);
      for (int dy = -m; dy <= m; ++dy) {
        int yy = cy + dy;
        if (yy < 0 || yy >= GRID) continue;
        bool yface = (dy == -m || dy == m);
        int rowbase = (zz * GRID + yy) * GRID;
        if (zface || yface) {
          int x0 = max(0, cx - m), x1 = min(GRID - 1, cx + m);
          int ks = offsets[rowbase + x0], ke = offsets[rowbase + x1 + 1];
          for (int k = ks + r; k < ke; k += LPG) {
            float4 p = sorted[k];
            float psq = sqnorm3(p.x, p.y, p.z);
            float dv = dist2(q.x, q.y, q.z, qs, p.x, p.y, p.z, psq);
            tp.insert(packkey(dv, __float_as_int(p.w)));
          }
        } else {
          int xa = cx - m, xb = cx + m;
          if (xa >= 0) {
            int ks = offsets[rowbase + xa], ke = offsets[rowbase + xa + 1];
            for (int k = ks + r; k < ke; k += LPG) {
              float4 p = sorted[k];
              float psq = sqnorm3(p.x, p.y, p.z);
              float dv = dist2(q.x, q.y, q.z, qs, p.x, p.y, p.z, psq);
              tp.insert(packkey(dv, __float_as_int(p.w)));
            }
          }
          if (xb < GRID) {
            int ks = offsets[rowbase + xb], ke = offsets[rowbase + xb + 1];
            for (int k = ks + r; k < ke; k += LPG) {
              float4 p = sorted[k];
              float psq = sqnorm3(p.x, p.y, p.z);
              float dv = dist2(q.x, q.y, q.z, qs, p.x, p.y, p.z, psq);
              tp.insert(packkey(dv, __float_as_int(p.w)));
            }
          }
        }
      }
    }
    B = unpackd(tp.k4);
    B = fminf(B, __shfl_xor(B, 1));
    B = fminf(B, __shfl_xor(B, 2));
    B = fminf(B, __shfl_xor(B, 4));
  }

  // exact final merge of the 8 disjoint per-lane lists
  tp.merge_xor(1);
  tp.merge_xor(2);
  tp.merge_xor(4);

  if (r == 0) {
    nbh[t * 5 + 0] = unpackj(tp.k0);
    nbh[t * 5 + 1] = unpackj(tp.k1);
    nbh[t * 5 + 2] = unpackj(tp.k2);
    nbh[t * 5 + 3] = unpackj(tp.k3);
    nbh[t * 5 + 4] = unpackj(tp.k4);
  }
}

// Classify: replicate cov->tridiag + the ssteqr first-segment QL/QR branch
// (uniform, ~200 instr) and partition points so solver waves are branch-pure.
// QL-points fill perm from the front, QR-points from the back.
__global__ __launch_bounds__(256) void classify_kernel(
    const float* __restrict__ P, const float4* __restrict__ sorted,
    const int* __restrict__ nbh, int* __restrict__ perm,
    int* __restrict__ cnts, int n) {
#pragma clang fp contract(off)
  int t = blockIdx.x * 256 + threadIdx.x;
  if (t >= n) return;
  int io = __float_as_int(sorted[t].w);
  int nb[KNN_K] = {nbh[t * 5 + 0], nbh[t * 5 + 1], nbh[t * 5 + 2],
                   nbh[t * 5 + 3], nbh[t * 5 + 4]};
  float dif[KNN_K][3];
  float dd[3], ee[2];
  float taui, v2;
  tridiag_of(P, io, nb, dif, dd, ee, &taui, &v2);

  // First-segment selection as in ssteqr (n=3, l1=1):
  const float eps = EPSF;
  int m = 3;
  for (int q = 1; q <= 2; ++q) {
    float tst = fabsf(ee[q - 1]);
    if (tst == 0.f) { m = q; break; }
    if (tst <= (sqrtf(fabsf(dd[q - 1])) * sqrtf(fabsf(dd[q]))) * eps) { m = q; break; }
  }
  bool qr = false;
  if (m > 1) {
    // l=1, lend=m; swap if |d[lend-1]| < |d[l-1]|  -> QR
    qr = (fabsf(dd[m - 1]) < fabsf(dd[0]));
  }
  if (qr) {
    int pos = atomicAdd(&cnts[1], 1);
    perm[n - 1 - pos] = t;
  } else {
    int pos = atomicAdd(&cnts[0], 1);
    perm[pos] = t;
  }
}

// Solver: 1 thread/point, 64-thr blocks over 256 CUs (R20 best geometry),
// processing in branch-partitioned order via perm.
__global__ __launch_bounds__(64) void solver_kernel(
    const float* __restrict__ P, const float4* __restrict__ sorted,
    const int* __restrict__ nbh, const int* __restrict__ perm,
    float* __restrict__ out, int n) {
  int s = blockIdx.x * 64 + threadIdx.x;
  if (s >= n) return;
  int t = perm[s];
  int io = __float_as_int(sorted[t].w);
  lrf_one(P, out, io,
          nbh[t * 5 + 0], nbh[t * 5 + 1], nbh[t * 5 + 2],
          nbh[t * 5 + 3], nbh[t * 5 + 4]);
}

// ======================= brute-force fallback =======================

__global__ __launch_bounds__(TPB) void knn_brute_kernel(
    const float* __restrict__ P, float* __restrict__ out, int n) {
  __shared__ float4 tile[TILE];

  const int tid = threadIdx.x;
  const int p = tid >> 4;
  const int s = tid & 15;
  const int i = blockIdx.x * PPB + p;
  const int iq = (i < n) ? i : (n - 1);

  const float qx = P[iq * 3 + 0];
  const float qy = P[iq * 3 + 1];
  const float qz = P[iq * 3 + 2];
  const float qs = sqnorm3(qx, qy, qz);

  Key5 t;
  t.init();

  for (int base = 0; base < n; base += TILE) {
    int cnt = min(TILE, n - base);
    __syncthreads();
    for (int j = tid; j < cnt; j += TPB) {
      float x = P[(base + j) * 3 + 0];
      float y = P[(base + j) * 3 + 1];
      float z = P[(base + j) * 3 + 2];
      tile[j] = make_float4(x, y, z, sqnorm3(x, y, z));
    }
    __syncthreads();
    for (int j = s; j < cnt; j += STR) {
      float4 q = tile[j];
      t.insert(packkey(dist2(qx, qy, qz, qs, q.x, q.y, q.z, q.w), base + j));
    }
  }

#pragma unroll
  for (int rnd = 0; rnd < 4; ++rnd) {
    t.merge_xor(1 << rnd);
  }

  if (s == 0 && i < n) {
    lrf_one(P, out, i, unpackj(t.k0), unpackj(t.k1), unpackj(t.k2),
            unpackj(t.k3), unpackj(t.k4));
  }
}

}  // namespace

extern "C" void kernel_launch(void* const* d_in, const int* in_sizes, int n_in,
                              void* d_out, int out_size, void* d_ws, size_t ws_size,
                              hipStream_t stream) {
  (void)n_in; (void)out_size;
  const float* P = (const float*)d_in[0];
  float* out = (float*)d_out;
  const int n = in_sizes[0] / 3;
  if (n <= 0) return;

  // Workspace: sorted f4[n] | offsets int[CELLS+1] | cursor int[CELLS] |
  //            nbh int[5n] | perm int[n] | cnts int[2]
  size_t off_sorted = 0;
  size_t off_counts = off_sorted + (size_t)n * sizeof(float4);
  size_t off_cursor = off_counts + ((size_t)(CELLS + 1) * sizeof(int) + 15) / 16 * 16;
  size_t off_nbh = off_cursor + (size_t)CELLS * sizeof(int);
  size_t off_perm = off_nbh + (size_t)n * 5 * sizeof(int);
  size_t off_cnts = off_perm + (size_t)n * sizeof(int);
  size_t need = off_cnts + 16;

  if (ws_size >= need && n >= KNN_K) {
    char* base = (char*)d_ws;
    float4* sorted = (float4*)(base + off_sorted);
    int* counts = (int*)(base + off_counts);
    int* cursor = (int*)(base + off_cursor);
    int* nbh = (int*)(base + off_nbh);
    int* perm = (int*)(base + off_perm);
    int* cnts = (int*)(base + off_cnts);

    hipMemsetAsync(counts, 0, (size_t)CELLS * sizeof(int), stream);
    hipMemsetAsync(cnts, 0, 2 * sizeof(int), stream);
    hist_kernel<<<(n + 255) / 256, 256, 0, stream>>>(P, counts, n);
    scan_kernel<<<1, 256, 0, stream>>>(counts, cursor);
    scatter_kernel<<<(n + 255) / 256, 256, 0, stream>>>(P, cursor, sorted, n);
    const int ppb = 256 / LPG;  // 32 points per block
    knn_kernel<<<(n + ppb - 1) / ppb, 256, 0, stream>>>(sorted, counts, nbh, n);
    classify_kernel<<<(n + 255) / 256, 256, 0, stream>>>(P, sorted, nbh, perm, cnts, n);
    solver_kernel<<<(n + 63) / 64, 64, 0, stream>>>(P, sorted, nbh, perm, out, n);
  } else {
    const int blocks = (n + PPB - 1) / PPB;
    knn_brute_kernel<<<blocks, TPB, 0, stream>>>(P, out, n);
  }
}